// Round 1
// baseline (505.605 us; speedup 1.0000x reference)
//
#include <hip/hip_runtime.h>

#define N 8192
#define DIM 128
#define EPS 10.0f
#define AINV (1.0f / 8192.0f)
#define IC 128            // i-chunks for K^T matvec partials
#define ROWS_PER_CHUNK 64 // 8192 / IC

typedef __attribute__((ext_vector_type(8))) short short8;
typedef __attribute__((ext_vector_type(4))) float f32x4;

static __device__ __forceinline__ unsigned short f2bf(float f) {
  unsigned int b = __float_as_uint(f);
  unsigned int lsb = (b >> 16) & 1u;
  b += 0x7fffu + lsb; // round-to-nearest-even
  return (unsigned short)(b >> 16);
}

// Convert x,y -> bf16 and compute fp32 squared norms. One wave per row.
__global__ __launch_bounds__(64) void k_convert(const float* __restrict__ x, const float* __restrict__ y,
                                                unsigned short* __restrict__ xb, unsigned short* __restrict__ yb,
                                                float* __restrict__ x2, float* __restrict__ y2) {
  int r = blockIdx.x;
  int l = threadIdx.x;
  const float* src = (r < N) ? (x + (size_t)r * DIM) : (y + (size_t)(r - N) * DIM);
  float2 f = ((const float2*)src)[l];
  unsigned short* dst = (r < N) ? (xb + (size_t)r * DIM) : (yb + (size_t)(r - N) * DIM);
  ushort2 h; h.x = f2bf(f.x); h.y = f2bf(f.y);
  ((ushort2*)dst)[l] = h;
  float s = f.x * f.x + f.y * f.y;
#pragma unroll
  for (int off = 32; off >= 1; off >>= 1) s += __shfl_down(s, off);
  if (l == 0) { if (r < N) x2[r] = s; else y2[r - N] = s; }
}

// K[i][j] = exp(-cdist(x_i,y_j)/EPS), stored at D[1 + i*N + j].
// 128x128 tile per block, 4 waves, mfma_f32_16x16x32_bf16, XOR-swizzled LDS.
__global__ __launch_bounds__(256) void k_buildK(const unsigned short* __restrict__ xb,
                                                const unsigned short* __restrict__ yb,
                                                const float* __restrict__ x2, const float* __restrict__ y2,
                                                float* __restrict__ D) {
  __shared__ uint4 xs[128 * 16];
  __shared__ uint4 ys[128 * 16];
  const int i0 = blockIdx.y * 128;
  const int j0 = blockIdx.x * 128;
  const int tid = threadIdx.x;
  const uint4* xg = (const uint4*)xb + (size_t)i0 * 16; // 16 x 16B chunks per row (128 bf16)
  const uint4* yg = (const uint4*)yb + (size_t)j0 * 16;
#pragma unroll
  for (int s = 0; s < 8; ++s) {
    int q = tid + s * 256;           // 0..2047
    int r = q >> 4, cc = q & 15;
    int sw = r * 16 + (cc ^ (r & 7)); // st-16B XOR swizzle across 8 rows
    xs[sw] = xg[q];
    ys[sw] = yg[q];
  }
  __syncthreads();
  const int wid = tid >> 6, lane = tid & 63;
  const int wr = (wid >> 1) * 64, wc = (wid & 1) * 64;
  const int lhi = lane >> 4, llo = lane & 15;
  f32x4 zero = {0.f, 0.f, 0.f, 0.f};
  f32x4 acc[4][4];
#pragma unroll
  for (int m = 0; m < 4; ++m)
#pragma unroll
    for (int n = 0; n < 4; ++n) acc[m][n] = zero;
#pragma unroll
  for (int kk = 0; kk < 4; ++kk) {
    int ck = kk * 4 + lhi;
    short8 af[4], bfr[4];
#pragma unroll
    for (int m = 0; m < 4; ++m) {
      int rx = wr + m * 16 + llo;
      af[m] = *(const short8*)&xs[rx * 16 + (ck ^ (rx & 7))];
      int ry = wc + m * 16 + llo;
      bfr[m] = *(const short8*)&ys[ry * 16 + (ck ^ (ry & 7))];
    }
#pragma unroll
    for (int m = 0; m < 4; ++m)
#pragma unroll
      for (int n = 0; n < 4; ++n)
        acc[m][n] = __builtin_amdgcn_mfma_f32_16x16x32_bf16(af[m], bfr[n], acc[m][n], 0, 0, 0);
  }
#pragma unroll
  for (int m = 0; m < 4; ++m) {
#pragma unroll
    for (int n = 0; n < 4; ++n) {
#pragma unroll
      for (int r = 0; r < 4; ++r) {
        int i = i0 + wr + m * 16 + lhi * 4 + r; // C/D: col=lane&15, row=(lane>>4)*4+reg
        int j = j0 + wc + n * 16 + llo;
        float d2 = x2[i] + y2[j] - 2.0f * acc[m][n][r];
        d2 = fmaxf(d2, 0.0f);
        float c = sqrtf(d2);
        D[1 + (size_t)i * N + j] = __expf(-c * (1.0f / EPS));
      }
    }
  }
}

// u_new[i] = a / dot(K[i,:], v). One block per row; aligned float4 reads of D
// with the element->j remap (j = 4t+e-1; j==-1 belongs to the previous row, skipped).
__global__ __launch_bounds__(256) void k_u_update(const float* __restrict__ D, const float* __restrict__ v,
                                                  float* __restrict__ u, float* __restrict__ apart,
                                                  const int* __restrict__ done) {
  if (*done) return;
  __shared__ float red[256];
  const int i = blockIdx.x;
  const int tid = threadIdx.x;
  const float4* row4 = (const float4*)D + (size_t)i * 2048;
  float sum = 0.f;
  for (int t = tid; t <= 2048; t += 256) {
    if (t < 2048) {
      float4 q = row4[t];
      int jb = 4 * t - 1;
      if (jb >= 0) sum += q.x * v[jb];
      sum += q.y * v[jb + 1];
      sum += q.z * v[jb + 2];
      sum += q.w * v[jb + 3];
    } else {
      // last element of row i sits at D[(i+1)*N] (valid for i==N-1 too: D[N*N])
      sum += D[(size_t)(i + 1) * N] * v[N - 1];
    }
  }
  red[tid] = sum;
  __syncthreads();
  for (int s = 128; s > 0; s >>= 1) {
    if (tid < s) red[tid] += red[tid + s];
    __syncthreads();
  }
  if (tid == 0) {
    float unew = AINV / red[0];
    float d = unew - u[i];
    apart[i] = d * d;
    u[i] = unew;
  }
}

// Partial K^T@u: block (g, ic) covers float4-columns c = g*256+tid over 64 rows.
// float4 element e -> column j = 4c+e-1; c==0,e==0 is K[i-1][N-1] -> column N-1.
__global__ __launch_bounds__(256) void k_vpart(const float* __restrict__ D, const float* __restrict__ u,
                                               float* __restrict__ vpart, const int* __restrict__ done) {
  if (*done) return;
  const int g = blockIdx.x;  // 0..7
  const int ic = blockIdx.y; // 0..IC-1
  const int tid = threadIdx.x;
  const int c = g * 256 + tid; // 0..2047
  const int i0 = ic * ROWS_PER_CHUNK;
  const float4* D4 = (const float4*)D;
  float s0 = 0.f, s1 = 0.f, s2 = 0.f, s3 = 0.f;
  for (int i = i0; i < i0 + ROWS_PER_CHUNK; ++i) {
    float4 q = D4[(size_t)i * 2048 + c];
    float ui = u[i];
    if (c == 0) {
      if (i > 0) s0 += q.x * u[i - 1]; // K[i-1][N-1]
    } else {
      s0 += q.x * ui;
    }
    s1 += q.y * ui;
    s2 += q.z * ui;
    s3 += q.w * ui;
  }
  if (c == 0 && ic == IC - 1) s0 += D[(size_t)N * N] * u[N - 1]; // K[N-1][N-1]
  int jb = 4 * c - 1;
  float* vp = vpart + (size_t)ic * N;
  vp[(c == 0) ? (N - 1) : jb] = s0;
  vp[jb + 1] = s1;
  vp[jb + 2] = s2;
  vp[jb + 3] = s3;
}

__global__ __launch_bounds__(256) void k_v_update(const float* __restrict__ vpart, float* __restrict__ v,
                                                  const int* __restrict__ done) {
  if (*done) return;
  int j = blockIdx.x * 256 + threadIdx.x;
  float s = 0.f;
  for (int ic = 0; ic < IC; ++ic) s += vpart[(size_t)ic * N + j];
  v[j] = AINV / s;
}

__global__ __launch_bounds__(256) void k_check(const float* __restrict__ apart, int* __restrict__ done) {
  if (*done) return;
  __shared__ float red[256];
  float s = 0.f;
  for (int t = threadIdx.x; t < N; t += 256) s += apart[t];
  red[threadIdx.x] = s;
  __syncthreads();
  for (int st = 128; st > 0; st >>= 1) {
    if (threadIdx.x < st) red[threadIdx.x] += red[threadIdx.x + st];
    __syncthreads();
  }
  if (threadIdx.x == 0 && red[0] < 1e-12f) *done = 1; // ||u_new-u|| < 1e-6
}

__global__ void k_init(float* u, float* v, int* done, double* accs) {
  int idx = blockIdx.x * 256 + threadIdx.x;
  if (idx < N) { u[idx] = 1.f; v[idx] = 1.f; }
  if (idx == 0) { *done = 0; accs[0] = 0.0; accs[1] = 0.0; }
}

// In-place K -> P, accumulate transport = sum(P*C) with C = -EPS*log(K),
// and ent_raw = sum(P*log(P+1e-9)).
__global__ __launch_bounds__(256) void k_final(float* __restrict__ D, const float* __restrict__ u,
                                               const float* __restrict__ v, double* __restrict__ accs) {
  __shared__ double r0[256], r1[256];
  double lc = 0.0, le = 0.0;
  size_t stride = (size_t)gridDim.x * 256;
  for (size_t e = (size_t)blockIdx.x * 256 + threadIdx.x; e < (size_t)N * N; e += stride) {
    float k = D[1 + e];
    int i = (int)(e >> 13);
    int j = (int)(e & 8191);
    float p = u[i] * k * v[j];
    D[1 + e] = p;
    float c = -EPS * __logf(k);
    lc += (double)(p * c);
    le += (double)(p * __logf(p + 1e-9f));
  }
  r0[threadIdx.x] = lc;
  r1[threadIdx.x] = le;
  __syncthreads();
  for (int s = 128; s > 0; s >>= 1) {
    if (threadIdx.x < s) {
      r0[threadIdx.x] += r0[threadIdx.x + s];
      r1[threadIdx.x] += r1[threadIdx.x + s];
    }
    __syncthreads();
  }
  if (threadIdx.x == 0) {
    atomicAdd(&accs[0], r0[0]);
    atomicAdd(&accs[1], r1[0]);
  }
}

__global__ void k_write_div(float* D, const double* accs) {
  if (threadIdx.x == 0 && blockIdx.x == 0)
    D[0] = (float)(accs[0] - (double)EPS * accs[1]); // transport + EPS*entropy
}

extern "C" void kernel_launch(void* const* d_in, const int* in_sizes, int n_in,
                              void* d_out, int out_size, void* d_ws, size_t ws_size,
                              hipStream_t stream) {
  const float* x = (const float*)d_in[0];
  const float* y = (const float*)d_in[1];
  float* D = (float*)d_out;
  char* w = (char*)d_ws;
  unsigned short* xb = (unsigned short*)w;             // 2 MB (only live until buildK)
  unsigned short* yb = (unsigned short*)(w + 2097152); // 2 MB
  float* vpart = (float*)w;                            // 4 MB, reuses xb/yb region after buildK
  float* fb = (float*)(w + 4194304);
  float* x2 = fb;
  float* y2 = fb + 8192;
  float* u = fb + 16384;
  float* v = fb + 24576;
  float* apart = fb + 32768;
  double* accs = (double*)(w + 4194304 + 5 * 32768);
  int* done = (int*)(accs + 2);

  k_init<<<32, 256, 0, stream>>>(u, v, done, accs);
  k_convert<<<2 * N, 64, 0, stream>>>(x, y, xb, yb, x2, y2);
  dim3 gb(64, 64);
  k_buildK<<<gb, 256, 0, stream>>>(xb, yb, x2, y2, D);
  for (int it = 0; it < 10; ++it) {
    k_u_update<<<N, 256, 0, stream>>>(D, v, u, apart, done);
    k_vpart<<<dim3(8, IC), 256, 0, stream>>>(D, u, vpart, done);
    k_v_update<<<32, 256, 0, stream>>>(vpart, v, done);
    k_check<<<1, 256, 0, stream>>>(apart, done);
  }
  k_final<<<2048, 256, 0, stream>>>(D, u, v, accs);
  k_write_div<<<1, 64, 0, stream>>>(D, accs);
}

// Round 4
// 471.184 us; speedup vs baseline: 1.0731x; 1.0731x over previous
//
#include <hip/hip_runtime.h>

#define N 8192
#define DIM 128
#define EPS 10.0f
#define AINV (1.0f / 8192.0f)
#define C1 (-0.14426950408889634f) // -log2(e)/EPS : K = exp2(c*C1)

typedef __attribute__((ext_vector_type(8))) short short8;
typedef __attribute__((ext_vector_type(4))) float f32x4;

static __device__ __forceinline__ unsigned short f2bf(float f) {
  unsigned int b = __float_as_uint(f);
  unsigned int lsb = (b >> 16) & 1u;
  b += 0x7fffu + lsb; // round-to-nearest-even
  return (unsigned short)(b >> 16);
}

// Convert x,y -> bf16 and compute fp32 squared norms. One wave per row.
__global__ __launch_bounds__(64) void k_convert(const float* __restrict__ x, const float* __restrict__ y,
                                                unsigned short* __restrict__ xb, unsigned short* __restrict__ yb,
                                                float* __restrict__ x2, float* __restrict__ y2) {
  int r = blockIdx.x;
  int l = threadIdx.x;
  const float* src = (r < N) ? (x + (size_t)r * DIM) : (y + (size_t)(r - N) * DIM);
  float2 f = ((const float2*)src)[l];
  unsigned short* dst = (r < N) ? (xb + (size_t)r * DIM) : (yb + (size_t)(r - N) * DIM);
  ushort2 h; h.x = f2bf(f.x); h.y = f2bf(f.y);
  ((ushort2*)dst)[l] = h;
  float s = f.x * f.x + f.y * f.y;
#pragma unroll
  for (int off = 32; off >= 1; off >>= 1) s += __shfl_down(s, off);
  if (l == 0) { if (r < N) x2[r] = s; else y2[r - N] = s; }
}

__global__ void k_init(float* u, float* v, int* done, int* pend, double* accs) {
  int idx = blockIdx.x * 256 + threadIdx.x;
  if (idx < N) { u[idx] = 1.f; v[idx] = 1.f; }
  if (idx == 0) { *done = 0; *pend = 0; accs[0] = 0.0; accs[1] = 0.0; }
}

// One matvec pass with on-the-fly K recompute.
// Block (jc, ic): rows i0..i0+127 (ic), cols jc*1024..+1023. Each wave owns a
// 64-row x 64-col quadrant per subtile; the partial rowsum over its column
// half goes to slot q = jc*2 + (wid&1):  vpart[q*N + i]. Exactly one writer
// lane per (q, i) -> race-free plain stores.
__global__ __launch_bounds__(256) void k_pass(const unsigned short* __restrict__ Ab,
                                              const unsigned short* __restrict__ Bb,
                                              const float* __restrict__ a2, const float* __restrict__ b2,
                                              const float* __restrict__ w,
                                              float* __restrict__ vpart,
                                              const int* __restrict__ done) {
  if (*done) return;
  __shared__ uint4 as_[128 * 16];
  __shared__ uint4 bs[128 * 16];
  const int ic = blockIdx.y; // 0..63 row chunk
  const int jc = blockIdx.x; // 0..7  col window
  const int i0 = ic * 128;
  const int tid = threadIdx.x;
  const uint4* ag = (const uint4*)Ab + (size_t)i0 * 16;
#pragma unroll
  for (int s = 0; s < 8; ++s) {
    int q = tid + s * 256;
    int r = q >> 4, cc = q & 15;
    as_[r * 16 + (cc ^ (r & 7))] = ag[q];
  }
  __syncthreads();
  const int wid = tid >> 6, lane = tid & 63;
  const int wr = (wid >> 1) * 64, wc = (wid & 1) * 64;
  const int lhi = lane >> 4, llo = lane & 15;
  // Hoist sc-invariant A fragments into registers (16 x short8 = 64 VGPRs).
  short8 afr[4][4]; // [kk][m]
#pragma unroll
  for (int kk = 0; kk < 4; ++kk)
#pragma unroll
    for (int m = 0; m < 4; ++m) {
      int rx = wr + m * 16 + llo;
      afr[kk][m] = *(const short8*)&as_[rx * 16 + ((kk * 4 + lhi) ^ (rx & 7))];
    }
  float a2v[4][4], rsum[4][4];
#pragma unroll
  for (int m = 0; m < 4; ++m)
#pragma unroll
    for (int r = 0; r < 4; ++r) {
      a2v[m][r] = a2[i0 + wr + m * 16 + lhi * 4 + r];
      rsum[m][r] = 0.f;
    }
  for (int sc = 0; sc < 8; ++sc) {
    const int j0 = jc * 1024 + sc * 128;
    const uint4* bg = (const uint4*)Bb + (size_t)j0 * 16;
    __syncthreads();
#pragma unroll
    for (int s = 0; s < 8; ++s) {
      int q = tid + s * 256;
      int r = q >> 4, cc = q & 15;
      bs[r * 16 + (cc ^ (r & 7))] = bg[q];
    }
    __syncthreads();
    float wv[4], b2v[4];
#pragma unroll
    for (int n = 0; n < 4; ++n) {
      int j = j0 + wc + n * 16 + llo;
      wv[n] = w[j];
      b2v[n] = b2[j];
    }
    f32x4 acc[4][4];
    f32x4 zero = {0.f, 0.f, 0.f, 0.f};
#pragma unroll
    for (int m = 0; m < 4; ++m)
#pragma unroll
      for (int n = 0; n < 4; ++n) acc[m][n] = zero;
#pragma unroll
    for (int kk = 0; kk < 4; ++kk) {
      short8 bfr[4];
#pragma unroll
      for (int n = 0; n < 4; ++n) {
        int ry = wc + n * 16 + llo;
        bfr[n] = *(const short8*)&bs[ry * 16 + ((kk * 4 + lhi) ^ (ry & 7))];
      }
#pragma unroll
      for (int m = 0; m < 4; ++m)
#pragma unroll
        for (int n = 0; n < 4; ++n)
          acc[m][n] = __builtin_amdgcn_mfma_f32_16x16x32_bf16(afr[kk][m], bfr[n], acc[m][n], 0, 0, 0);
    }
#pragma unroll
    for (int m = 0; m < 4; ++m)
#pragma unroll
      for (int n = 0; n < 4; ++n)
#pragma unroll
        for (int r = 0; r < 4; ++r) {
          float d2 = fmaf(-2.f, acc[m][n][r], a2v[m][r] + b2v[n]);
          float c = sqrtf(fmaxf(d2, 0.f));
          rsum[m][r] = fmaf(exp2f(c * C1), wv[n], rsum[m][r]);
        }
  }
  // Reduce across the 16 llo lanes (same row, different columns within the
  // wave's 64-col half).
#pragma unroll
  for (int m = 0; m < 4; ++m)
#pragma unroll
    for (int r = 0; r < 4; ++r) {
      float s = rsum[m][r];
      s += __shfl_xor(s, 1);
      s += __shfl_xor(s, 2);
      s += __shfl_xor(s, 4);
      s += __shfl_xor(s, 8);
      rsum[m][r] = s;
    }
  if (llo == 0) {
    float* vp = vpart + (size_t)(jc * 2 + (wid & 1)) * N;
#pragma unroll
    for (int m = 0; m < 4; ++m)
#pragma unroll
      for (int r = 0; r < 4; ++r)
        vp[i0 + wr + m * 16 + lhi * 4 + r] = rsum[m][r];
  }
}

// Fold the 16 partial slots per row, update u or v, and handle the latch.
// Single block: in-LDS norm reduction, no atomics.
__global__ __launch_bounds__(1024) void k_reduce(const float* __restrict__ vpart, float* __restrict__ uv,
                                                 int* __restrict__ pend, int* __restrict__ done, int is_u) {
  if (*done) return;
  __shared__ float red[1024];
  const int tid = threadIdx.x;
  float dd = 0.f;
  for (int i = tid; i < N; i += 1024) {
    float s = 0.f;
#pragma unroll
    for (int q = 0; q < 16; ++q) s += vpart[(size_t)q * N + i];
    float nw = AINV / s;
    float d = nw - uv[i];
    uv[i] = nw;
    dd += d * d;
  }
  if (is_u) {
    red[tid] = dd;
    __syncthreads();
    for (int st = 512; st > 0; st >>= 1) {
      if (tid < st) red[tid] += red[tid + st];
      __syncthreads();
    }
    if (tid == 0) *pend = (red[0] < 1e-12f) ? 1 : 0; // ||u_new-u|| < 1e-6
  } else {
    if (tid == 0 && *pend) *done = 1; // commit AFTER v update (converging step kept)
  }
}

// Recompute K tile, write P = u_i*K*v_j, accumulate transport (sum P*c) and
// raw entropy (sum P*log(P+1e-9)) in double.
__global__ __launch_bounds__(256) void k_final(const unsigned short* __restrict__ xb,
                                               const unsigned short* __restrict__ yb,
                                               const float* __restrict__ x2, const float* __restrict__ y2,
                                               const float* __restrict__ u, const float* __restrict__ v,
                                               float* __restrict__ D, double* __restrict__ accs) {
  __shared__ uint4 xs[128 * 16];
  __shared__ uint4 ys[128 * 16];
  const int i0 = blockIdx.y * 128;
  const int j0 = blockIdx.x * 128;
  const int tid = threadIdx.x;
  const uint4* xg = (const uint4*)xb + (size_t)i0 * 16;
  const uint4* yg = (const uint4*)yb + (size_t)j0 * 16;
#pragma unroll
  for (int s = 0; s < 8; ++s) {
    int q = tid + s * 256;
    int r = q >> 4, cc = q & 15;
    int sw = r * 16 + (cc ^ (r & 7));
    xs[sw] = xg[q];
    ys[sw] = yg[q];
  }
  __syncthreads();
  const int wid = tid >> 6, lane = tid & 63;
  const int wr = (wid >> 1) * 64, wc = (wid & 1) * 64;
  const int lhi = lane >> 4, llo = lane & 15;
  float x2v[4][4], uvv[4][4], y2v[4], vv[4];
#pragma unroll
  for (int m = 0; m < 4; ++m)
#pragma unroll
    for (int r = 0; r < 4; ++r) {
      int i = i0 + wr + m * 16 + lhi * 4 + r;
      x2v[m][r] = x2[i];
      uvv[m][r] = u[i];
    }
#pragma unroll
  for (int n = 0; n < 4; ++n) {
    int j = j0 + wc + n * 16 + llo;
    y2v[n] = y2[j];
    vv[n] = v[j];
  }
  f32x4 acc[4][4];
  f32x4 zero = {0.f, 0.f, 0.f, 0.f};
#pragma unroll
  for (int m = 0; m < 4; ++m)
#pragma unroll
    for (int n = 0; n < 4; ++n) acc[m][n] = zero;
#pragma unroll
  for (int kk = 0; kk < 4; ++kk) {
    short8 af[4], bfr[4];
#pragma unroll
    for (int m = 0; m < 4; ++m) {
      int rx = wr + m * 16 + llo;
      af[m] = *(const short8*)&xs[rx * 16 + ((kk * 4 + lhi) ^ (rx & 7))];
      int ry = wc + m * 16 + llo;
      bfr[m] = *(const short8*)&ys[ry * 16 + ((kk * 4 + lhi) ^ (ry & 7))];
    }
#pragma unroll
    for (int m = 0; m < 4; ++m)
#pragma unroll
      for (int n = 0; n < 4; ++n)
        acc[m][n] = __builtin_amdgcn_mfma_f32_16x16x32_bf16(af[m], bfr[n], acc[m][n], 0, 0, 0);
  }
  float lc = 0.f, le = 0.f;
#pragma unroll
  for (int m = 0; m < 4; ++m) {
#pragma unroll
    for (int n = 0; n < 4; ++n) {
#pragma unroll
      for (int r = 0; r < 4; ++r) {
        int i = i0 + wr + m * 16 + lhi * 4 + r;
        int j = j0 + wc + n * 16 + llo;
        float d2 = fmaf(-2.f, acc[m][n][r], x2v[m][r] + y2v[n]);
        float c = sqrtf(fmaxf(d2, 0.f));
        float k = exp2f(c * C1);
        float p = uvv[m][r] * k * vv[n];
        D[1 + (size_t)i * N + j] = p;
        lc = fmaf(p, c, lc);
        le = fmaf(p, __logf(p + 1e-9f), le);
      }
    }
  }
  // Overlay the double reduction onto xs (all LDS reads are done).
  __syncthreads();
  double* r0 = (double*)xs;
  double* r1 = r0 + 256;
  r0[tid] = (double)lc;
  r1[tid] = (double)le;
  __syncthreads();
  for (int s = 128; s > 0; s >>= 1) {
    if (tid < s) {
      r0[tid] += r0[tid + s];
      r1[tid] += r1[tid + s];
    }
    __syncthreads();
  }
  if (tid == 0) {
    atomicAdd(&accs[0], r0[0]);
    atomicAdd(&accs[1], r1[0]);
  }
}

__global__ void k_write_div(float* D, const double* accs) {
  if (threadIdx.x == 0 && blockIdx.x == 0)
    D[0] = (float)(accs[0] - (double)EPS * accs[1]); // transport + EPS*entropy
}

extern "C" void kernel_launch(void* const* d_in, const int* in_sizes, int n_in,
                              void* d_out, int out_size, void* d_ws, size_t ws_size,
                              hipStream_t stream) {
  const float* x = (const float*)d_in[0];
  const float* y = (const float*)d_in[1];
  float* D = (float*)d_out;
  char* w = (char*)d_ws;
  unsigned short* xb = (unsigned short*)w;             // 2 MB
  unsigned short* yb = (unsigned short*)(w + 2097152); // 2 MB
  float* fb = (float*)(w + 4194304);
  float* x2 = fb;
  float* y2 = fb + 8192;
  float* u = fb + 16384;
  float* v = fb + 24576;
  double* accs = (double*)(fb + 32768);
  int* done = (int*)(accs + 2);
  int* pend = done + 1;
  // 16 matvec partial slots live in the (not-yet-written) P region of d_out.
  float* vpart = D + 1;

  k_init<<<32, 256, 0, stream>>>(u, v, done, pend, accs);
  k_convert<<<2 * N, 64, 0, stream>>>(x, y, xb, yb, x2, y2);
  for (int it = 0; it < 10; ++it) {
    k_pass<<<dim3(8, 64), 256, 0, stream>>>(xb, yb, x2, y2, v, vpart, done);
    k_reduce<<<1, 1024, 0, stream>>>(vpart, u, pend, done, 1);
    k_pass<<<dim3(8, 64), 256, 0, stream>>>(yb, xb, y2, x2, u, vpart, done);
    k_reduce<<<1, 1024, 0, stream>>>(vpart, v, pend, done, 0);
  }
  k_final<<<dim3(64, 64), 256, 0, stream>>>(xb, yb, x2, y2, u, v, D, accs);
  k_write_div<<<1, 64, 0, stream>>>(D, accs);
}

// Round 5
// 297.908 us; speedup vs baseline: 1.6972x; 1.5816x over previous
//
#include <hip/hip_runtime.h>

#define N 8192
#define DIM 128
#define EPS 10.0f
#define AINV (1.0f / 8192.0f)
#define C1 (-0.14426950408889634f) // -log2(e)/EPS : K = exp2(c*C1)

typedef __attribute__((ext_vector_type(8))) short short8;
typedef __attribute__((ext_vector_type(4))) float f32x4;

static __device__ __forceinline__ unsigned short f2bf(float f) {
  unsigned int b = __float_as_uint(f);
  unsigned int lsb = (b >> 16) & 1u;
  b += 0x7fffu + lsb; // round-to-nearest-even
  return (unsigned short)(b >> 16);
}

// Convert x,y -> bf16 and compute fp32 squared norms. One wave per row.
__global__ __launch_bounds__(64) void k_convert(const float* __restrict__ x, const float* __restrict__ y,
                                                unsigned short* __restrict__ xb, unsigned short* __restrict__ yb,
                                                float* __restrict__ x2, float* __restrict__ y2) {
  int r = blockIdx.x;
  int l = threadIdx.x;
  const float* src = (r < N) ? (x + (size_t)r * DIM) : (y + (size_t)(r - N) * DIM);
  float2 f = ((const float2*)src)[l];
  unsigned short* dst = (r < N) ? (xb + (size_t)r * DIM) : (yb + (size_t)(r - N) * DIM);
  ushort2 h; h.x = f2bf(f.x); h.y = f2bf(f.y);
  ((ushort2*)dst)[l] = h;
  float s = f.x * f.x + f.y * f.y;
#pragma unroll
  for (int off = 32; off >= 1; off >>= 1) s += __shfl_down(s, off);
  if (l == 0) { if (r < N) x2[r] = s; else y2[r - N] = s; }
}

// u=1; vpartB reconstructs to v=1 (slot0=AINV, rest 0 -> AINV*rcp(AINV)=1 exact);
// normp=1e30 (so un-run iterations never look converged); accs=0.
__global__ void k_init(float* u, float* vpartB, float* normp, double* accs) {
  int idx = blockIdx.x * 256 + threadIdx.x;
  if (idx < N) {
    u[idx] = 1.f;
    vpartB[idx] = AINV;
#pragma unroll
    for (int q = 1; q < 16; ++q) vpartB[q * N + idx] = 0.f;
  }
  if (idx < 80) normp[idx] = 1e30f;
  if (idx == 0) { accs[0] = 0.0; accs[1] = 0.0; }
}

// One Sinkhorn half-step with on-the-fly K recompute and fused vector rebuild.
// Block (jc, ic): rows i0=ic*128 of A, cols jc*1024..+1023 of B.
// Head: reconstruct w[j] = AINV*rcp(sum_q wpart[q*N+j]) for the window.
// Body: partial rowsum_i = sum_j exp(-dist(A_i,B_j)/EPS) * w_j  -> outpart slot
// q = jc*2 + (wid&1) (one writer lane per (q,i)).
// Designated blocks (ic==0, write_norm) also write u_arr and normp[t*8+jc].
// Latch: exit if any earlier iteration's norm^2 sum < 1e-12 (frozen thereafter).
__global__ __launch_bounds__(256) void k_pass(const unsigned short* __restrict__ Ab,
                                              const unsigned short* __restrict__ Bb,
                                              const float* __restrict__ a2, const float* __restrict__ b2,
                                              const float* __restrict__ wpart,
                                              float* __restrict__ outpart,
                                              float* __restrict__ u_arr,
                                              float* __restrict__ normp,
                                              int t, int write_norm) {
  for (int tt = 0; tt < t; ++tt) {
    float s = 0.f;
#pragma unroll
    for (int q = 0; q < 8; ++q) s += normp[tt * 8 + q];
    if (s < 1e-12f) return; // ||u_new-u|| < 1e-6 latched
  }
  __shared__ uint4 as_[128 * 16];
  __shared__ uint4 bs[128 * 16];
  __shared__ float wv_lds[1024];
  __shared__ float b2_lds[1024];
  __shared__ float red[256];
  const int ic = blockIdx.y; // 0..63 row chunk
  const int jc = blockIdx.x; // 0..7  col window
  const int i0 = ic * 128;
  const int tid = threadIdx.x;
  const uint4* ag = (const uint4*)Ab + (size_t)i0 * 16;
#pragma unroll
  for (int s = 0; s < 8; ++s) {
    int q = tid + s * 256;
    int r = q >> 4, cc = q & 15;
    as_[r * 16 + (cc ^ (r & 7))] = ag[q];
  }
  // Reconstruct this window's w (and b2) into LDS: thread tid owns 4 floats.
  {
    const float4* wp4 = (const float4*)wpart;
    int w4 = jc * 256 + tid;
    float4 s4 = wp4[w4];
#pragma unroll
    for (int q = 1; q < 16; ++q) {
      float4 p = wp4[(size_t)q * 2048 + w4];
      s4.x += p.x; s4.y += p.y; s4.z += p.z; s4.w += p.w;
    }
    float4 wn;
    wn.x = AINV * __builtin_amdgcn_rcpf(s4.x);
    wn.y = AINV * __builtin_amdgcn_rcpf(s4.y);
    wn.z = AINV * __builtin_amdgcn_rcpf(s4.z);
    wn.w = AINV * __builtin_amdgcn_rcpf(s4.w);
    ((float4*)wv_lds)[tid] = wn;
    ((float4*)b2_lds)[tid] = ((const float4*)b2)[w4];
    if (write_norm && ic == 0) {
      float4 uo = ((const float4*)u_arr)[w4];
      float dd = (wn.x - uo.x) * (wn.x - uo.x) + (wn.y - uo.y) * (wn.y - uo.y) +
                 (wn.z - uo.z) * (wn.z - uo.z) + (wn.w - uo.w) * (wn.w - uo.w);
      ((float4*)u_arr)[w4] = wn;
      red[tid] = dd;
      __syncthreads();
      for (int st = 128; st > 0; st >>= 1) {
        if (tid < st) red[tid] += red[tid + st];
        __syncthreads();
      }
      if (tid == 0) normp[t * 8 + jc] = red[0];
    }
  }
  __syncthreads();
  const int wid = tid >> 6, lane = tid & 63;
  const int wr = (wid >> 1) * 64, wc = (wid & 1) * 64;
  const int lhi = lane >> 4, llo = lane & 15;
  // Hoist sc-invariant A fragments into registers.
  short8 afr[4][4]; // [kk][m]
#pragma unroll
  for (int kk = 0; kk < 4; ++kk)
#pragma unroll
    for (int m = 0; m < 4; ++m) {
      int rx = wr + m * 16 + llo;
      afr[kk][m] = *(const short8*)&as_[rx * 16 + ((kk * 4 + lhi) ^ (rx & 7))];
    }
  float a2v[4][4], rsum[4][4];
#pragma unroll
  for (int m = 0; m < 4; ++m)
#pragma unroll
    for (int r = 0; r < 4; ++r) {
      a2v[m][r] = a2[i0 + wr + m * 16 + lhi * 4 + r];
      rsum[m][r] = 0.f;
    }
  for (int sc = 0; sc < 8; ++sc) {
    const int j0 = jc * 1024 + sc * 128;
    const uint4* bg = (const uint4*)Bb + (size_t)j0 * 16;
    __syncthreads();
#pragma unroll
    for (int s = 0; s < 8; ++s) {
      int q = tid + s * 256;
      int r = q >> 4, cc = q & 15;
      bs[r * 16 + (cc ^ (r & 7))] = bg[q];
    }
    __syncthreads();
    float wv[4], b2v[4];
#pragma unroll
    for (int n = 0; n < 4; ++n) {
      int jl = sc * 128 + wc + n * 16 + llo;
      wv[n] = wv_lds[jl];
      b2v[n] = b2_lds[jl];
    }
    f32x4 acc[4][4];
    f32x4 zero = {0.f, 0.f, 0.f, 0.f};
#pragma unroll
    for (int m = 0; m < 4; ++m)
#pragma unroll
      for (int n = 0; n < 4; ++n) acc[m][n] = zero;
#pragma unroll
    for (int kk = 0; kk < 4; ++kk) {
      short8 bfr[4];
#pragma unroll
      for (int n = 0; n < 4; ++n) {
        int ry = wc + n * 16 + llo;
        bfr[n] = *(const short8*)&bs[ry * 16 + ((kk * 4 + lhi) ^ (ry & 7))];
      }
#pragma unroll
      for (int m = 0; m < 4; ++m)
#pragma unroll
        for (int n = 0; n < 4; ++n)
          acc[m][n] = __builtin_amdgcn_mfma_f32_16x16x32_bf16(afr[kk][m], bfr[n], acc[m][n], 0, 0, 0);
    }
#pragma unroll
    for (int m = 0; m < 4; ++m)
#pragma unroll
      for (int n = 0; n < 4; ++n)
#pragma unroll
        for (int r = 0; r < 4; ++r) {
          float d2 = fmaf(-2.f, acc[m][n][r], a2v[m][r] + b2v[n]);
          float c = __builtin_amdgcn_sqrtf(fmaxf(d2, 0.f));
          rsum[m][r] = fmaf(__builtin_amdgcn_exp2f(c * C1), wv[n], rsum[m][r]);
        }
  }
#pragma unroll
  for (int m = 0; m < 4; ++m)
#pragma unroll
    for (int r = 0; r < 4; ++r) {
      float s = rsum[m][r];
      s += __shfl_xor(s, 1);
      s += __shfl_xor(s, 2);
      s += __shfl_xor(s, 4);
      s += __shfl_xor(s, 8);
      rsum[m][r] = s;
    }
  if (llo == 0) {
    float* vp = outpart + (size_t)(jc * 2 + (wid & 1)) * N;
#pragma unroll
    for (int m = 0; m < 4; ++m)
#pragma unroll
      for (int r = 0; r < 4; ++r)
        vp[i0 + wr + m * 16 + lhi * 4 + r] = rsum[m][r];
  }
}

// Recompute K tile, reconstruct v from vpartB, write P = u_i*K*v_j, accumulate
// transport (sum P*c) and raw entropy (sum P*log(P+1e-9)) in double.
__global__ __launch_bounds__(256) void k_final(const unsigned short* __restrict__ xb,
                                               const unsigned short* __restrict__ yb,
                                               const float* __restrict__ x2, const float* __restrict__ y2,
                                               const float* __restrict__ u, const float* __restrict__ vpartB,
                                               float* __restrict__ D, double* __restrict__ accs) {
  __shared__ uint4 xs[128 * 16];
  __shared__ uint4 ys[128 * 16];
  __shared__ float vv_lds[128];
  const int i0 = blockIdx.y * 128;
  const int j0 = blockIdx.x * 128;
  const int tid = threadIdx.x;
  const uint4* xg = (const uint4*)xb + (size_t)i0 * 16;
  const uint4* yg = (const uint4*)yb + (size_t)j0 * 16;
#pragma unroll
  for (int s = 0; s < 8; ++s) {
    int q = tid + s * 256;
    int r = q >> 4, cc = q & 15;
    int sw = r * 16 + (cc ^ (r & 7));
    xs[sw] = xg[q];
    ys[sw] = yg[q];
  }
  if (tid < 32) {
    const float4* vp4 = (const float4*)vpartB;
    int w4 = (j0 >> 2) + tid;
    float4 s4 = vp4[w4];
#pragma unroll
    for (int q = 1; q < 16; ++q) {
      float4 p = vp4[(size_t)q * 2048 + w4];
      s4.x += p.x; s4.y += p.y; s4.z += p.z; s4.w += p.w;
    }
    float4 vn;
    vn.x = AINV * __builtin_amdgcn_rcpf(s4.x);
    vn.y = AINV * __builtin_amdgcn_rcpf(s4.y);
    vn.z = AINV * __builtin_amdgcn_rcpf(s4.z);
    vn.w = AINV * __builtin_amdgcn_rcpf(s4.w);
    ((float4*)vv_lds)[tid] = vn;
  }
  __syncthreads();
  const int wid = tid >> 6, lane = tid & 63;
  const int wr = (wid >> 1) * 64, wc = (wid & 1) * 64;
  const int lhi = lane >> 4, llo = lane & 15;
  float x2v[4][4], uvv[4][4], y2v[4], vv[4];
#pragma unroll
  for (int m = 0; m < 4; ++m)
#pragma unroll
    for (int r = 0; r < 4; ++r) {
      int i = i0 + wr + m * 16 + lhi * 4 + r;
      x2v[m][r] = x2[i];
      uvv[m][r] = u[i];
    }
#pragma unroll
  for (int n = 0; n < 4; ++n) {
    int j = j0 + wc + n * 16 + llo;
    y2v[n] = y2[j];
    vv[n] = vv_lds[wc + n * 16 + llo];
  }
  f32x4 acc[4][4];
  f32x4 zero = {0.f, 0.f, 0.f, 0.f};
#pragma unroll
  for (int m = 0; m < 4; ++m)
#pragma unroll
    for (int n = 0; n < 4; ++n) acc[m][n] = zero;
#pragma unroll
  for (int kk = 0; kk < 4; ++kk) {
    short8 af[4], bfr[4];
#pragma unroll
    for (int m = 0; m < 4; ++m) {
      int rx = wr + m * 16 + llo;
      af[m] = *(const short8*)&xs[rx * 16 + ((kk * 4 + lhi) ^ (rx & 7))];
      int ry = wc + m * 16 + llo;
      bfr[m] = *(const short8*)&ys[ry * 16 + ((kk * 4 + lhi) ^ (ry & 7))];
    }
#pragma unroll
    for (int m = 0; m < 4; ++m)
#pragma unroll
      for (int n = 0; n < 4; ++n)
        acc[m][n] = __builtin_amdgcn_mfma_f32_16x16x32_bf16(af[m], bfr[n], acc[m][n], 0, 0, 0);
  }
  float lc = 0.f, le = 0.f;
#pragma unroll
  for (int m = 0; m < 4; ++m) {
#pragma unroll
    for (int n = 0; n < 4; ++n) {
#pragma unroll
      for (int r = 0; r < 4; ++r) {
        int i = i0 + wr + m * 16 + lhi * 4 + r;
        int j = j0 + wc + n * 16 + llo;
        float d2 = fmaf(-2.f, acc[m][n][r], x2v[m][r] + y2v[n]);
        float c = __builtin_amdgcn_sqrtf(fmaxf(d2, 0.f));
        float k = __builtin_amdgcn_exp2f(c * C1);
        float p = uvv[m][r] * k * vv[n];
        D[1 + (size_t)i * N + j] = p;
        lc = fmaf(p, c, lc);
        le = fmaf(p, __logf(p + 1e-9f), le);
      }
    }
  }
  // Overlay the double reduction onto xs (all LDS reads are done).
  __syncthreads();
  double* r0 = (double*)xs;
  double* r1 = r0 + 256;
  r0[tid] = (double)lc;
  r1[tid] = (double)le;
  __syncthreads();
  for (int s = 128; s > 0; s >>= 1) {
    if (tid < s) {
      r0[tid] += r0[tid + s];
      r1[tid] += r1[tid + s];
    }
    __syncthreads();
  }
  if (tid == 0) {
    atomicAdd(&accs[0], r0[0]);
    atomicAdd(&accs[1], r1[0]);
  }
}

__global__ void k_write_div(float* D, const double* accs) {
  if (threadIdx.x == 0 && blockIdx.x == 0)
    D[0] = (float)(accs[0] - (double)EPS * accs[1]); // transport + EPS*entropy
}

extern "C" void kernel_launch(void* const* d_in, const int* in_sizes, int n_in,
                              void* d_out, int out_size, void* d_ws, size_t ws_size,
                              hipStream_t stream) {
  const float* x = (const float*)d_in[0];
  const float* y = (const float*)d_in[1];
  float* D = (float*)d_out;
  char* w = (char*)d_ws;
  unsigned short* xb = (unsigned short*)w;             // 2 MB
  unsigned short* yb = (unsigned short*)(w + 2097152); // 2 MB
  float* fb = (float*)(w + 4194304);
  float* x2 = fb;                    // 8192
  float* y2 = fb + 8192;             // 8192
  float* u = fb + 16384;             // 8192
  float* vpartA = fb + 24576;        // 16*8192
  float* vpartB = vpartA + 16 * N;   // 16*8192
  float* normp = vpartB + 16 * N;    // 80
  double* accs = (double*)(normp + 96);

  k_init<<<32, 256, 0, stream>>>(u, vpartB, normp, accs);
  k_convert<<<2 * N, 64, 0, stream>>>(x, y, xb, yb, x2, y2);
  for (int it = 0; it < 10; ++it) {
    // u-half: rows=x, cols=y, w=v (from vpartB) -> vpartA (K@v partials)
    k_pass<<<dim3(8, 64), 256, 0, stream>>>(xb, yb, x2, y2, vpartB, vpartA, u, normp, it, 0);
    // v-half: rows=y, cols=x, w=u (from vpartA) -> vpartB (K^T@u partials);
    // designated blocks write u array + normp[it].
    k_pass<<<dim3(8, 64), 256, 0, stream>>>(yb, xb, y2, x2, vpartA, vpartB, u, normp, it, 1);
  }
  k_final<<<dim3(64, 64), 256, 0, stream>>>(xb, yb, x2, y2, u, vpartB, D, accs);
  k_write_div<<<1, 64, 0, stream>>>(D, accs);
}